// Round 12
// baseline (296.677 us; speedup 1.0000x reference)
//
#include <hip/hip_runtime.h>

#define NEG_SLOPE 0.01f

typedef __attribute__((ext_vector_type(8))) __bf16 bf16x8;
typedef __attribute__((ext_vector_type(4))) float  f32x4;

__device__ __forceinline__ unsigned short f2bf(float x) {
    unsigned u; __builtin_memcpy(&u, &x, 4);
    unsigned r = u + 0x7FFFu + ((u >> 16) & 1u);   // RNE
    return (unsigned short)(r >> 16);
}
__device__ __forceinline__ float bflo(unsigned u) {
    unsigned v = u << 16; float f; __builtin_memcpy(&f, &v, 4); return f;
}
__device__ __forceinline__ float bfhi(unsigned u) {
    unsigned v = u & 0xFFFF0000u; float f; __builtin_memcpy(&f, &v, 4); return f;
}
__device__ __forceinline__ float rfl_f(float x) {
    int i; __builtin_memcpy(&i, &x, 4);
    int r = __builtin_amdgcn_readfirstlane(i);
    float f; __builtin_memcpy(&f, &r, 4); return f;
}

// streaming stores (asm 'v' constraint needs register-class types, not structs)
__device__ __forceinline__ void stream_store8(void* p, unsigned long long v) {
    asm volatile("global_store_dwordx2 %0, %1, off sc0 sc1 nt"
                 :: "v"((unsigned long long)(__UINTPTR_TYPE__)p), "v"(v) : "memory");
}
__device__ __forceinline__ void stream_store16(void* p, f32x4 v) {
    asm volatile("global_store_dwordx4 %0, %1, off sc0 sc1 nt"
                 :: "v"((unsigned long long)(__UINTPTR_TYPE__)p), "v"(v) : "memory");
}

// ---------------------------------------------------------------------------
// K0: zero the degree array
// ---------------------------------------------------------------------------
__global__ void zero_kernel(int* __restrict__ p, int n) {
    int i = blockIdx.x * blockDim.x + threadIdx.x;
    if (i < n) p[i] = 0;
}

// ---------------------------------------------------------------------------
// K1a: pack all 512 projection columns as B^T bf16 [n=512][k=128].
// ---------------------------------------------------------------------------
__global__ __launch_bounds__(256) void bt_prep(
    const float* __restrict__ Wn, const float* __restrict__ We,
    short* __restrict__ Btg)
{
    int idx = blockIdx.x * 256 + threadIdx.x;   // 0..65535
    int n = idx >> 7, k = idx & 127;
    float v;
    if (n < 256)      v = Wn[(size_t)k * 256 + n];
    else if (n < 384) v = We[(size_t)k * 128 + (n - 256)];
    else              v = We[(size_t)(135 + k) * 128 + (n - 384)];
    Btg[(size_t)n * 128 + k] = (short)f2bf(v);
}

// ---------------------------------------------------------------------------
// K1b: MFMA projection GEMM: A[N,128](fp32->bf16) @ B[128,512]
// 64-row tiles, ct in blockIdx.y. Outputs interleaved PH record per node:
//   lane slots 0-1 = P cols {2l,2l+1}; slots 2-5 = h cols {4l..4l+3} (+bias)
// plus Qbf [N,128] bf16.
// ---------------------------------------------------------------------------
__global__ __launch_bounds__(256) void gemm_mfma(
    const float* __restrict__ A, const float* __restrict__ bn,
    const short* __restrict__ Btg, unsigned short* __restrict__ PH,
    unsigned short* __restrict__ Qbf, int N)
{
    __shared__ __align__(16) short Al[64 * 136];
    __shared__ __align__(16) short Bl[128 * 136];
    int t = threadIdx.x;
    int ct = blockIdx.y;
    int row0 = blockIdx.x * 64;

    #pragma unroll
    for (int i = 0; i < 8; i++) {
        int idx = t + i * 256;
        int fr = idx >> 5, fc4 = idx & 31;
        int row = row0 + fr;
        float4 v = make_float4(0.f, 0.f, 0.f, 0.f);
        if (row < N) v = *(const float4*)(A + (size_t)row * 128 + fc4 * 4);
        unsigned long long pk =  (unsigned long long)f2bf(v.x)
                              | ((unsigned long long)f2bf(v.y) << 16)
                              | ((unsigned long long)f2bf(v.z) << 32)
                              | ((unsigned long long)f2bf(v.w) << 48);
        *(unsigned long long*)&Al[fr * 136 + fc4 * 4] = pk;
    }
    #pragma unroll
    for (int i = 0; i < 8; i++) {
        int idx = t + i * 256;
        int r = idx >> 4, c8 = idx & 15;
        uint4 v = *(const uint4*)(Btg + (size_t)(ct * 128 + r) * 128 + c8 * 8);
        *(uint4*)&Bl[r * 136 + c8 * 8] = v;
    }
    __syncthreads();

    int w = t >> 6, l = t & 63;
    int lr = l & 15, lg = l >> 4;

    f32x4 acc[8];
    #pragma unroll
    for (int fc = 0; fc < 8; fc++) {
        acc[fc][0] = 0.f; acc[fc][1] = 0.f; acc[fc][2] = 0.f; acc[fc][3] = 0.f;
    }

    #pragma unroll
    for (int ks = 0; ks < 4; ks++) {
        int k0 = ks * 32 + lg * 8;
        bf16x8 a0 = *(const bf16x8*)&Al[(w * 16 + lr) * 136 + k0];
        #pragma unroll
        for (int fc = 0; fc < 8; fc++) {
            bf16x8 bb = *(const bf16x8*)&Bl[(fc * 16 + lr) * 136 + k0];
            acc[fc] = __builtin_amdgcn_mfma_f32_16x16x32_bf16(a0, bb, acc[fc], 0, 0, 0);
        }
    }

    #pragma unroll
    for (int fc = 0; fc < 8; fc++) {
        int col = fc * 16 + lr;
        float bias = (ct < 2) ? bn[ct * 128 + col] : 0.f;
        #pragma unroll
        for (int b = 0; b < 4; b++) {
            int row = row0 + w * 16 + lg * 4 + b;
            if (row >= N) continue;
            unsigned short bv = f2bf(acc[fc][b] + bias);
            if (ct < 2) {
                int col256 = ct * 128 + col;                    // h column
                PH[(size_t)row * 384 + (col256 >> 2) * 6 + 2 + (col256 & 3)] = bv;
            } else if (ct == 2) {
                PH[(size_t)row * 384 + (col >> 1) * 6 + (col & 1)] = bv;   // P
            } else {
                Qbf[(size_t)row * 128 + col] = bv;                         // Q
            }
        }
    }
}

// ---------------------------------------------------------------------------
// K2: scatter1 — one atomic pass: tmp[i] = slot of edge i within its dst list
// ---------------------------------------------------------------------------
__global__ void scatter1_kernel(const int* __restrict__ dst, int* __restrict__ deg,
                                unsigned short* __restrict__ tmp, int E) {
    int i = blockIdx.x * blockDim.x + threadIdx.x;
    if (i < E) tmp[i] = (unsigned short)atomicAdd(&deg[dst[i]], 1);
}

// ---------------------------------------------------------------------------
// K3a: per-1024-chunk sums of deg
// ---------------------------------------------------------------------------
__global__ __launch_bounds__(256) void scan_sum(
    const int* __restrict__ deg, int* __restrict__ bsum, int n)
{
    int b = blockIdx.x, t = threadIdx.x;
    int base = b * 1024 + t * 4;
    int s = 0;
    #pragma unroll
    for (int k = 0; k < 4; k++) { int i = base + k; if (i < n) s += deg[i]; }
    #pragma unroll
    for (int off = 32; off >= 1; off >>= 1) s += __shfl_xor(s, off);
    __shared__ int ws[4];
    if ((t & 63) == 0) ws[t >> 6] = s;
    __syncthreads();
    if (t == 0) bsum[b] = ws[0] + ws[1] + ws[2] + ws[3];
}

// ---------------------------------------------------------------------------
// K3b: scan_write — block sums its bsum prefix itself; last writes sentinel.
// ---------------------------------------------------------------------------
__global__ __launch_bounds__(256) void scan_write(
    const int* __restrict__ deg, const int* __restrict__ bsum,
    int* __restrict__ row_start, int n, int nb)
{
    int b = blockIdx.x, t = threadIdx.x, lane = t & 63, w = t >> 6;
    __shared__ int boff_s;
    if (t == 0) {
        int a = 0;
        for (int j = 0; j < b; j++) a += bsum[j];
        boff_s = a;
        if (b == nb - 1) row_start[n] = a + bsum[b];
    }
    __syncthreads();

    int base = b * 1024 + t * 4;
    int x0, x1, x2, x3;
    x0 = (base + 0 < n) ? deg[base + 0] : 0;
    x1 = (base + 1 < n) ? deg[base + 1] : 0;
    x2 = (base + 2 < n) ? deg[base + 2] : 0;
    x3 = (base + 3 < n) ? deg[base + 3] : 0;
    int tsum = x0 + x1 + x2 + x3;
    int inc = tsum;
    #pragma unroll
    for (int off = 1; off < 64; off <<= 1) {
        int v = __shfl_up(inc, off);
        if (lane >= off) inc += v;
    }
    int texcl = inc - tsum;
    __shared__ int wsum[4];
    if (lane == 63) wsum[w] = inc;
    __syncthreads();
    int wexcl = 0;
    #pragma unroll
    for (int ww = 0; ww < 4; ww++) if (ww < w) wexcl += wsum[ww];
    int p0 = boff_s + wexcl + texcl;
    int p1 = p0 + x0;
    int p2 = p1 + x1;
    int p3 = p2 + x2;
    if (base + 0 < n) row_start[base + 0] = p0;
    if (base + 1 < n) row_start[base + 1] = p1;
    if (base + 2 < n) row_start[base + 2] = p2;
    if (base + 3 < n) row_start[base + 3] = p3;
}

// ---------------------------------------------------------------------------
// K4: scatter2 — build full 48B edge record {e, src, ef[7], pad} at CSR slot.
// ef read SEQUENTIALLY here (dense), so fused needs no random ef gathers.
// No atomics: slot = row_start[dst] + tmp[i].
// ---------------------------------------------------------------------------
__global__ void scatter2_kernel(const int* __restrict__ dst, const int* __restrict__ src,
                                const float* __restrict__ ef,
                                const int* __restrict__ row_start,
                                const unsigned short* __restrict__ tmp,
                                int* __restrict__ rec, int E) {
    int i = blockIdx.x * blockDim.x + threadIdx.x;
    if (i < E) {
        int pos = row_start[dst[i]] + (int)tmp[i];
        int* rp = rec + (size_t)pos * 12;
        const float* ep = ef + (size_t)i * 7;
        float e0 = ep[0], e1 = ep[1], e2 = ep[2], e3 = ep[3];
        float e4 = ep[4], e5 = ep[5], e6 = ep[6];
        int4 a;
        a.x = i; a.y = src[i];
        __builtin_memcpy(&a.z, &e0, 4); __builtin_memcpy(&a.w, &e1, 4);
        *(int4*)rp = a;
        float4 b = make_float4(e2, e3, e4, e5);
        *(float4*)(rp + 4) = b;
        int c; __builtin_memcpy(&c, &e6, 4);
        rp[8] = c;
    }
}

// ---------------------------------------------------------------------------
// K5: FUSED edge-MLP + online-softmax + aggregation. One wave per dst node.
// Quad-stream unroll-4. Per edge: 3 broadcast record loads + 1 PH gather
// (was 9 VMEM: es + 7 random ef + PH). ef values live in SGPRs.
// ---------------------------------------------------------------------------
__global__ __launch_bounds__(256) void fused_kernel(
    const int* __restrict__ row_start, const int* __restrict__ REC,
    const unsigned short* __restrict__ PH, const unsigned short* __restrict__ Qbf,
    const float* __restrict__ We, const float* __restrict__ Wa,
    float* __restrict__ f_out, float* __restrict__ out, int N)
{
    int t = threadIdx.x;
    int lane = t & 63;
    int n = (int)((blockIdx.x * blockDim.x + t) >> 6);
    if (n >= N) return;
    int c0 = lane * 2;

    float* Obase = out + (size_t)n * 256 + lane * 4;
    int nu = __builtin_amdgcn_readfirstlane(n);
    int start = row_start[nu];
    int deg   = row_start[nu + 1] - start;
    if (deg == 0) {
        f32x4 z; z[0] = 0.f; z[1] = 0.f; z[2] = 0.f; z[3] = 0.f;
        stream_store16(Obase, z);
        return;
    }

    float wf0[7], wf1[7];
    #pragma unroll
    for (int j = 0; j < 7; j++) {
        wf0[j] = We[(size_t)(128 + j) * 128 + c0];
        wf1[j] = We[(size_t)(128 + j) * 128 + c0 + 1];
    }
    int j0 = c0 & 31, j1 = j0 + 1;
    float wv0 = Wa[j0] + Wa[32 + j0] + Wa[64 + j0] + Wa[96 + j0];
    float wv1 = Wa[j1] + Wa[32 + j1] + Wa[64 + j1] + Wa[96 + j1];

    unsigned qu = ((const unsigned*)Qbf)[(size_t)n * 64 + lane];
    float q0 = bflo(qu), q1 = bfhi(qu);

    #define DSTR(X) \
        float m##X = -1e30f, d##X = 0.f;                                  \
        float4 a##X = make_float4(0.f, 0.f, 0.f, 0.f);                    \
        int e##X = 0; unsigned pu##X = 0; uint2 hu##X = make_uint2(0u,0u);\
        float f##X##0=0.f,f##X##1=0.f,f##X##2=0.f,f##X##3=0.f,            \
              f##X##4=0.f,f##X##5=0.f,f##X##6=0.f;
    #define DNXT(X) \
        int e##X = 0; unsigned pu##X = 0; uint2 hu##X = make_uint2(0u,0u);\
        float f##X##0=0.f,f##X##1=0.f,f##X##2=0.f,f##X##3=0.f,            \
              f##X##4=0.f,f##X##5=0.f,f##X##6=0.f;

    #define LOADE(pos, X) {                                               \
        const int* rp_ = REC + (size_t)(start + (pos)) * 12;              \
        int4   r0_ = *(const int4*)rp_;                                   \
        float4 r1_ = *(const float4*)(rp_ + 4);                           \
        float  r2_; { int rc_ = rp_[8]; __builtin_memcpy(&r2_, &rc_, 4); }\
        e##X = __builtin_amdgcn_readfirstlane(r0_.x);                     \
        int s_ = __builtin_amdgcn_readfirstlane(r0_.y);                   \
        uint3 ph_ = *(const uint3*)(PH + (size_t)s_ * 384 + lane * 6);    \
        pu##X = ph_.x;                                                    \
        hu##X = make_uint2(ph_.y, ph_.z);                                 \
        { float t0_; __builtin_memcpy(&t0_, &r0_.z, 4); f##X##0 = rfl_f(t0_); } \
        { float t1_; __builtin_memcpy(&t1_, &r0_.w, 4); f##X##1 = rfl_f(t1_); } \
        f##X##2 = rfl_f(r1_.x); f##X##3 = rfl_f(r1_.y);                   \
        f##X##4 = rfl_f(r1_.z); f##X##5 = rfl_f(r1_.w);                   \
        f##X##6 = rfl_f(r2_); }

    #define PROC(X) {                                                     \
        float a0 = bflo(pu##X) + q0, a1 = bfhi(pu##X) + q1;               \
        a0 = fmaf(f##X##0, wf0[0], a0); a1 = fmaf(f##X##0, wf1[0], a1);   \
        a0 = fmaf(f##X##1, wf0[1], a0); a1 = fmaf(f##X##1, wf1[1], a1);   \
        a0 = fmaf(f##X##2, wf0[2], a0); a1 = fmaf(f##X##2, wf1[2], a1);   \
        a0 = fmaf(f##X##3, wf0[3], a0); a1 = fmaf(f##X##3, wf1[3], a1);   \
        a0 = fmaf(f##X##4, wf0[4], a0); a1 = fmaf(f##X##4, wf1[4], a1);   \
        a0 = fmaf(f##X##5, wf0[5], a0); a1 = fmaf(f##X##5, wf1[5], a1);   \
        a0 = fmaf(f##X##6, wf0[6], a0); a1 = fmaf(f##X##6, wf1[6], a1);   \
        float v0 = a0 > 0.f ? a0 : NEG_SLOPE * a0;                        \
        float v1 = a1 > 0.f ? a1 : NEG_SLOPE * a1;                        \
        float2 fv_ = make_float2(v0, v1);                                 \
        unsigned long long u_;                                            \
        __builtin_memcpy(&u_, &fv_, 8);                                   \
        stream_store8(f_out + (size_t)e##X * 128 + c0, u_);               \
        float p_ = fmaf(v0, wv0, v1 * wv1);                               \
        p_ += __shfl_xor(p_, 8);                                          \
        p_ += __shfl_xor(p_, 4);                                          \
        p_ += __shfl_xor(p_, 2);                                          \
        p_ += __shfl_xor(p_, 1);                                          \
        float nm_ = fmaxf(m##X, p_);                                      \
        float sc_ = __expf(m##X - nm_);                                   \
        float pe_ = __expf(p_ - nm_);                                     \
        d##X = d##X * sc_ + pe_;                                          \
        float hx0 = bflo(hu##X.x), hx1 = bfhi(hu##X.x);                   \
        float hx2 = bflo(hu##X.y), hx3 = bfhi(hu##X.y);                   \
        a##X.x = fmaf(a##X.x, sc_, pe_ * hx0);                            \
        a##X.y = fmaf(a##X.y, sc_, pe_ * hx1);                            \
        a##X.z = fmaf(a##X.z, sc_, pe_ * hx2);                            \
        a##X.w = fmaf(a##X.w, sc_, pe_ * hx3);                            \
        m##X = nm_; }

    #define ROT(X, Y) { e##X = e##Y; pu##X = pu##Y; hu##X = hu##Y;        \
        f##X##0 = f##Y##0; f##X##1 = f##Y##1; f##X##2 = f##Y##2;          \
        f##X##3 = f##Y##3; f##X##4 = f##Y##4; f##X##5 = f##Y##5;          \
        f##X##6 = f##Y##6; }

    DSTR(A) DSTR(B) DSTR(C) DSTR(D)

    LOADE(0, A);
    if (deg > 1) LOADE(1, B);
    if (deg > 2) LOADE(2, C);
    if (deg > 3) LOADE(3, D);

    for (int k = 0;; k++) {
        int base = 4 * k;
        DNXT(An) DNXT(Bn) DNXT(Cn) DNXT(Dn)
        if (base + 4 < deg) LOADE(base + 4, An);
        if (base + 5 < deg) LOADE(base + 5, Bn);
        if (base + 6 < deg) LOADE(base + 6, Cn);
        if (base + 7 < deg) LOADE(base + 7, Dn);

        PROC(A);
        if (base + 1 < deg) PROC(B);
        if (base + 2 < deg) PROC(C);
        if (base + 3 < deg) PROC(D);

        if (base + 4 >= deg) break;
        ROT(A, An); ROT(B, Bn); ROT(C, Cn); ROT(D, Dn);
    }

    float nm = fmaxf(fmaxf(mA, mB), fmaxf(mC, mD));
    float scA = __expf(mA - nm), scB = __expf(mB - nm);
    float scC = __expf(mC - nm), scD = __expf(mD - nm);
    float den = dA * scA + dB * scB + dC * scC + dD * scD;
    float r = 1.f / den;
    f32x4 acc;
    acc[0] = (aA.x * scA + aB.x * scB + aC.x * scC + aD.x * scD) * r;
    acc[1] = (aA.y * scA + aB.y * scB + aC.y * scC + aD.y * scD) * r;
    acc[2] = (aA.z * scA + aB.z * scB + aC.z * scC + aD.z * scD) * r;
    acc[3] = (aA.w * scA + aB.w * scB + aC.w * scC + aD.w * scD) * r;
    stream_store16(Obase, acc);

    #undef DSTR
    #undef DNXT
    #undef LOADE
    #undef PROC
    #undef ROT
}

// ---------------------------------------------------------------------------
extern "C" void kernel_launch(void* const* d_in, const int* in_sizes, int n_in,
                              void* d_out, int out_size, void* d_ws, size_t ws_size,
                              hipStream_t stream)
{
    const float* nfeats = (const float*)d_in[0];
    const float* efeats = (const float*)d_in[1];
    const int*   src    = (const int*)d_in[2];
    const int*   dst    = (const int*)d_in[3];
    const float* Wn     = (const float*)d_in[4];
    const float* bn     = (const float*)d_in[5];
    const float* We     = (const float*)d_in[6];
    const float* Wa     = (const float*)d_in[7];

    int N = in_sizes[0] / 128;
    int E = in_sizes[2];

    char* ws = (char*)d_ws;
    size_t off = 0;
    unsigned short* PH  = (unsigned short*)(ws + off); off += (size_t)N * 384 * 2;
    unsigned short* Qbf = (unsigned short*)(ws + off); off += (size_t)N * 128 * 2;
    short* Btg   = (short*)(ws + off); off += (size_t)512 * 128 * 2;
    int* REC       = (int*)(ws + off); off += (size_t)E * 48;
    unsigned short* tmp = (unsigned short*)(ws + off); off += (size_t)E * 2;
    int* deg       = (int*)(ws + off); off += (size_t)(N + 1) * 4;
    int* row_start = (int*)(ws + off); off += (size_t)(N + 1) * 4;
    int* bsum      = (int*)(ws + off); off += 1024;

    float* h_out = (float*)d_out;                       // [N, 4, 64]
    float* f_out = (float*)d_out + (size_t)N * 256;     // [E, 4, 32]

    zero_kernel<<<(N + 255) / 256, 256, 0, stream>>>(deg, N);

    bt_prep<<<256, 256, 0, stream>>>(Wn, We, Btg);

    dim3 g2((N + 63) / 64, 4);
    gemm_mfma<<<g2, 256, 0, stream>>>(nfeats, bn, Btg, PH, Qbf, N);

    scatter1_kernel<<<(E + 255) / 256, 256, 0, stream>>>(dst, deg, tmp, E);

    int nb = (N + 1023) / 1024;
    scan_sum<<<nb, 256, 0, stream>>>(deg, bsum, N);
    scan_write<<<nb, 256, 0, stream>>>(deg, bsum, row_start, N, nb);

    scatter2_kernel<<<(E + 255) / 256, 256, 0, stream>>>(dst, src, efeats,
                                                         row_start, tmp, REC, E);

    fused_kernel<<<(N + 3) / 4, 256, 0, stream>>>(row_start, REC,
                                                  PH, Qbf, We, Wa,
                                                  f_out, h_out, N);
}

// Round 14
// 295.458 us; speedup vs baseline: 1.0041x; 1.0041x over previous
//
#include <hip/hip_runtime.h>

#define NEG_SLOPE 0.01f

typedef __attribute__((ext_vector_type(8))) __bf16 bf16x8;
typedef __attribute__((ext_vector_type(4))) float  f32x4;

__device__ __forceinline__ unsigned short f2bf(float x) {
    unsigned u; __builtin_memcpy(&u, &x, 4);
    unsigned r = u + 0x7FFFu + ((u >> 16) & 1u);   // RNE
    return (unsigned short)(r >> 16);
}
__device__ __forceinline__ float bflo(unsigned u) {
    unsigned v = u << 16; float f; __builtin_memcpy(&f, &v, 4); return f;
}
__device__ __forceinline__ float bfhi(unsigned u) {
    unsigned v = u & 0xFFFF0000u; float f; __builtin_memcpy(&f, &v, 4); return f;
}
__device__ __forceinline__ float rfl_f(float x) {
    int i; __builtin_memcpy(&i, &x, 4);
    int r = __builtin_amdgcn_readfirstlane(i);
    float f; __builtin_memcpy(&f, &r, 4); return f;
}

// streaming stores (asm 'v' constraint needs register-class types, not structs)
__device__ __forceinline__ void stream_store8(void* p, unsigned long long v) {
    asm volatile("global_store_dwordx2 %0, %1, off sc0 sc1 nt"
                 :: "v"((unsigned long long)(__UINTPTR_TYPE__)p), "v"(v) : "memory");
}
__device__ __forceinline__ void stream_store16(void* p, f32x4 v) {
    asm volatile("global_store_dwordx4 %0, %1, off sc0 sc1 nt"
                 :: "v"((unsigned long long)(__UINTPTR_TYPE__)p), "v"(v) : "memory");
}

// ---------------------------------------------------------------------------
// K0: zero the degree array
// ---------------------------------------------------------------------------
__global__ void zero_kernel(int* __restrict__ p, int n) {
    int i = blockIdx.x * blockDim.x + threadIdx.x;
    if (i < n) p[i] = 0;
}

// ---------------------------------------------------------------------------
// K1a: pack all 512 projection columns as B^T bf16 [n=512][k=128].
// ---------------------------------------------------------------------------
__global__ __launch_bounds__(256) void bt_prep(
    const float* __restrict__ Wn, const float* __restrict__ We,
    short* __restrict__ Btg)
{
    int idx = blockIdx.x * 256 + threadIdx.x;   // 0..65535
    int n = idx >> 7, k = idx & 127;
    float v;
    if (n < 256)      v = Wn[(size_t)k * 256 + n];
    else if (n < 384) v = We[(size_t)k * 128 + (n - 256)];
    else              v = We[(size_t)(135 + k) * 128 + (n - 384)];
    Btg[(size_t)n * 128 + k] = (short)f2bf(v);
}

// ---------------------------------------------------------------------------
// K1b: MFMA projection GEMM: A[N,128](fp32->bf16) @ B[128,512]
// 64-row tiles, ct in blockIdx.y. Outputs interleaved PH record per node:
//   lane slots 0-1 = P cols {2l,2l+1}; slots 2-5 = h cols {4l..4l+3} (+bias)
// plus Qbf [N,128] bf16.
// ---------------------------------------------------------------------------
__global__ __launch_bounds__(256) void gemm_mfma(
    const float* __restrict__ A, const float* __restrict__ bn,
    const short* __restrict__ Btg, unsigned short* __restrict__ PH,
    unsigned short* __restrict__ Qbf, int N)
{
    __shared__ __align__(16) short Al[64 * 136];
    __shared__ __align__(16) short Bl[128 * 136];
    int t = threadIdx.x;
    int ct = blockIdx.y;
    int row0 = blockIdx.x * 64;

    #pragma unroll
    for (int i = 0; i < 8; i++) {
        int idx = t + i * 256;
        int fr = idx >> 5, fc4 = idx & 31;
        int row = row0 + fr;
        float4 v = make_float4(0.f, 0.f, 0.f, 0.f);
        if (row < N) v = *(const float4*)(A + (size_t)row * 128 + fc4 * 4);
        unsigned long long pk =  (unsigned long long)f2bf(v.x)
                              | ((unsigned long long)f2bf(v.y) << 16)
                              | ((unsigned long long)f2bf(v.z) << 32)
                              | ((unsigned long long)f2bf(v.w) << 48);
        *(unsigned long long*)&Al[fr * 136 + fc4 * 4] = pk;
    }
    #pragma unroll
    for (int i = 0; i < 8; i++) {
        int idx = t + i * 256;
        int r = idx >> 4, c8 = idx & 15;
        uint4 v = *(const uint4*)(Btg + (size_t)(ct * 128 + r) * 128 + c8 * 8);
        *(uint4*)&Bl[r * 136 + c8 * 8] = v;
    }
    __syncthreads();

    int w = t >> 6, l = t & 63;
    int lr = l & 15, lg = l >> 4;

    f32x4 acc[8];
    #pragma unroll
    for (int fc = 0; fc < 8; fc++) {
        acc[fc][0] = 0.f; acc[fc][1] = 0.f; acc[fc][2] = 0.f; acc[fc][3] = 0.f;
    }

    #pragma unroll
    for (int ks = 0; ks < 4; ks++) {
        int k0 = ks * 32 + lg * 8;
        bf16x8 a0 = *(const bf16x8*)&Al[(w * 16 + lr) * 136 + k0];
        #pragma unroll
        for (int fc = 0; fc < 8; fc++) {
            bf16x8 bb = *(const bf16x8*)&Bl[(fc * 16 + lr) * 136 + k0];
            acc[fc] = __builtin_amdgcn_mfma_f32_16x16x32_bf16(a0, bb, acc[fc], 0, 0, 0);
        }
    }

    #pragma unroll
    for (int fc = 0; fc < 8; fc++) {
        int col = fc * 16 + lr;
        float bias = (ct < 2) ? bn[ct * 128 + col] : 0.f;
        #pragma unroll
        for (int b = 0; b < 4; b++) {
            int row = row0 + w * 16 + lg * 4 + b;
            if (row >= N) continue;
            unsigned short bv = f2bf(acc[fc][b] + bias);
            if (ct < 2) {
                int col256 = ct * 128 + col;                    // h column
                PH[(size_t)row * 384 + (col256 >> 2) * 6 + 2 + (col256 & 3)] = bv;
            } else if (ct == 2) {
                PH[(size_t)row * 384 + (col >> 1) * 6 + (col & 1)] = bv;   // P
            } else {
                Qbf[(size_t)row * 128 + col] = bv;                         // Q
            }
        }
    }
}

// ---------------------------------------------------------------------------
// K2: scatter1 — one atomic pass: tmp[i] = slot of edge i within its dst list
// ---------------------------------------------------------------------------
__global__ void scatter1_kernel(const int* __restrict__ dst, int* __restrict__ deg,
                                unsigned short* __restrict__ tmp, int E) {
    int i = blockIdx.x * blockDim.x + threadIdx.x;
    if (i < E) tmp[i] = (unsigned short)atomicAdd(&deg[dst[i]], 1);
}

// ---------------------------------------------------------------------------
// K3a: per-1024-chunk sums of deg
// ---------------------------------------------------------------------------
__global__ __launch_bounds__(256) void scan_sum(
    const int* __restrict__ deg, int* __restrict__ bsum, int n)
{
    int b = blockIdx.x, t = threadIdx.x;
    int base = b * 1024 + t * 4;
    int s = 0;
    #pragma unroll
    for (int k = 0; k < 4; k++) { int i = base + k; if (i < n) s += deg[i]; }
    #pragma unroll
    for (int off = 32; off >= 1; off >>= 1) s += __shfl_xor(s, off);
    __shared__ int ws[4];
    if ((t & 63) == 0) ws[t >> 6] = s;
    __syncthreads();
    if (t == 0) bsum[b] = ws[0] + ws[1] + ws[2] + ws[3];
}

// ---------------------------------------------------------------------------
// K3b: scan_write — block sums its bsum prefix itself; last writes sentinel.
// ---------------------------------------------------------------------------
__global__ __launch_bounds__(256) void scan_write(
    const int* __restrict__ deg, const int* __restrict__ bsum,
    int* __restrict__ row_start, int n, int nb)
{
    int b = blockIdx.x, t = threadIdx.x, lane = t & 63, w = t >> 6;
    __shared__ int boff_s;
    if (t == 0) {
        int a = 0;
        for (int j = 0; j < b; j++) a += bsum[j];
        boff_s = a;
        if (b == nb - 1) row_start[n] = a + bsum[b];
    }
    __syncthreads();

    int base = b * 1024 + t * 4;
    int x0, x1, x2, x3;
    x0 = (base + 0 < n) ? deg[base + 0] : 0;
    x1 = (base + 1 < n) ? deg[base + 1] : 0;
    x2 = (base + 2 < n) ? deg[base + 2] : 0;
    x3 = (base + 3 < n) ? deg[base + 3] : 0;
    int tsum = x0 + x1 + x2 + x3;
    int inc = tsum;
    #pragma unroll
    for (int off = 1; off < 64; off <<= 1) {
        int v = __shfl_up(inc, off);
        if (lane >= off) inc += v;
    }
    int texcl = inc - tsum;
    __shared__ int wsum[4];
    if (lane == 63) wsum[w] = inc;
    __syncthreads();
    int wexcl = 0;
    #pragma unroll
    for (int ww = 0; ww < 4; ww++) if (ww < w) wexcl += wsum[ww];
    int p0 = boff_s + wexcl + texcl;
    int p1 = p0 + x0;
    int p2 = p1 + x1;
    int p3 = p2 + x2;
    if (base + 0 < n) row_start[base + 0] = p0;
    if (base + 1 < n) row_start[base + 1] = p1;
    if (base + 2 < n) row_start[base + 2] = p2;
    if (base + 3 < n) row_start[base + 3] = p3;
}

// ---------------------------------------------------------------------------
// K4: scatter2 — build full 48B edge record {e, src, ef[7], pad} at CSR slot.
// ---------------------------------------------------------------------------
__global__ void scatter2_kernel(const int* __restrict__ dst, const int* __restrict__ src,
                                const float* __restrict__ ef,
                                const int* __restrict__ row_start,
                                const unsigned short* __restrict__ tmp,
                                int* __restrict__ rec, int E) {
    int i = blockIdx.x * blockDim.x + threadIdx.x;
    if (i < E) {
        int pos = row_start[dst[i]] + (int)tmp[i];
        int* rp = rec + (size_t)pos * 12;
        const float* ep = ef + (size_t)i * 7;
        float e0 = ep[0], e1 = ep[1], e2 = ep[2], e3 = ep[3];
        float e4 = ep[4], e5 = ep[5], e6 = ep[6];
        int4 a;
        a.x = i; a.y = src[i];
        __builtin_memcpy(&a.z, &e0, 4); __builtin_memcpy(&a.w, &e1, 4);
        *(int4*)rp = a;
        float4 b = make_float4(e2, e3, e4, e5);
        *(float4*)(rp + 4) = b;
        int c; __builtin_memcpy(&c, &e6, 4);
        rp[8] = c;
    }
}

// ---------------------------------------------------------------------------
// K5: FUSED edge-MLP + online-softmax + aggregation.
// ONE WAVE = ONE BLOCK = ONE NODE (64 threads): no 4-wave retire coupling,
// 50k schedulable blocks -> scheduler can pack toward 32 waves/CU and
// overlap one wave's gather stalls with other waves' VALU.
// ---------------------------------------------------------------------------
__global__ __launch_bounds__(64) void fused_kernel(
    const int* __restrict__ row_start, const int* __restrict__ REC,
    const unsigned short* __restrict__ PH, const unsigned short* __restrict__ Qbf,
    const float* __restrict__ We, const float* __restrict__ Wa,
    float* __restrict__ f_out, float* __restrict__ out, int N)
{
    int lane = threadIdx.x;
    int n = blockIdx.x;
    if (n >= N) return;
    int c0 = lane * 2;

    float* Obase = out + (size_t)n * 256 + lane * 4;
    int start = row_start[n];
    int deg   = row_start[n + 1] - start;
    if (deg == 0) {
        f32x4 z; z[0] = 0.f; z[1] = 0.f; z[2] = 0.f; z[3] = 0.f;
        stream_store16(Obase, z);
        return;
    }

    float wf0[7], wf1[7];
    #pragma unroll
    for (int j = 0; j < 7; j++) {
        wf0[j] = We[(size_t)(128 + j) * 128 + c0];
        wf1[j] = We[(size_t)(128 + j) * 128 + c0 + 1];
    }
    int j0 = c0 & 31, j1 = j0 + 1;
    float wv0 = Wa[j0] + Wa[32 + j0] + Wa[64 + j0] + Wa[96 + j0];
    float wv1 = Wa[j1] + Wa[32 + j1] + Wa[64 + j1] + Wa[96 + j1];

    unsigned qu = ((const unsigned*)Qbf)[(size_t)n * 64 + lane];
    float q0 = bflo(qu), q1 = bfhi(qu);

    #define DSTR(X) \
        float m##X = -1e30f, d##X = 0.f;                                  \
        float4 a##X = make_float4(0.f, 0.f, 0.f, 0.f);                    \
        int e##X = 0; unsigned pu##X = 0; uint2 hu##X = make_uint2(0u,0u);\
        float f##X##0=0.f,f##X##1=0.f,f##X##2=0.f,f##X##3=0.f,            \
              f##X##4=0.f,f##X##5=0.f,f##X##6=0.f;
    #define DNXT(X) \
        int e##X = 0; unsigned pu##X = 0; uint2 hu##X = make_uint2(0u,0u);\
        float f##X##0=0.f,f##X##1=0.f,f##X##2=0.f,f##X##3=0.f,            \
              f##X##4=0.f,f##X##5=0.f,f##X##6=0.f;

    #define LOADE(pos, X) {                                               \
        const int* rp_ = REC + (size_t)(start + (pos)) * 12;              \
        int4   r0_ = *(const int4*)rp_;                                   \
        float4 r1_ = *(const float4*)(rp_ + 4);                           \
        float  r2_; { int rc_ = rp_[8]; __builtin_memcpy(&r2_, &rc_, 4); }\
        e##X = __builtin_amdgcn_readfirstlane(r0_.x);                     \
        int s_ = __builtin_amdgcn_readfirstlane(r0_.y);                   \
        uint3 ph_ = *(const uint3*)(PH + (size_t)s_ * 384 + lane * 6);    \
        pu##X = ph_.x;                                                    \
        hu##X = make_uint2(ph_.y, ph_.z);                                 \
        { float t0_; __builtin_memcpy(&t0_, &r0_.z, 4); f##X##0 = rfl_f(t0_); } \
        { float t1_; __builtin_memcpy(&t1_, &r0_.w, 4); f##X##1 = rfl_f(t1_); } \
        f##X##2 = rfl_f(r1_.x); f##X##3 = rfl_f(r1_.y);                   \
        f##X##4 = rfl_f(r1_.z); f##X##5 = rfl_f(r1_.w);                   \
        f##X##6 = rfl_f(r2_); }

    #define PROC(X) {                                                     \
        float a0 = bflo(pu##X) + q0, a1 = bfhi(pu##X) + q1;               \
        a0 = fmaf(f##X##0, wf0[0], a0); a1 = fmaf(f##X##0, wf1[0], a1);   \
        a0 = fmaf(f##X##1, wf0[1], a0); a1 = fmaf(f##X##1, wf1[1], a1);   \
        a0 = fmaf(f##X##2, wf0[2], a0); a1 = fmaf(f##X##2, wf1[2], a1);   \
        a0 = fmaf(f##X##3, wf0[3], a0); a1 = fmaf(f##X##3, wf1[3], a1);   \
        a0 = fmaf(f##X##4, wf0[4], a0); a1 = fmaf(f##X##4, wf1[4], a1);   \
        a0 = fmaf(f##X##5, wf0[5], a0); a1 = fmaf(f##X##5, wf1[5], a1);   \
        a0 = fmaf(f##X##6, wf0[6], a0); a1 = fmaf(f##X##6, wf1[6], a1);   \
        float v0 = a0 > 0.f ? a0 : NEG_SLOPE * a0;                        \
        float v1 = a1 > 0.f ? a1 : NEG_SLOPE * a1;                        \
        float2 fv_ = make_float2(v0, v1);                                 \
        unsigned long long u_;                                            \
        __builtin_memcpy(&u_, &fv_, 8);                                   \
        stream_store8(f_out + (size_t)e##X * 128 + c0, u_);               \
        float p_ = fmaf(v0, wv0, v1 * wv1);                               \
        p_ += __shfl_xor(p_, 8);                                          \
        p_ += __shfl_xor(p_, 4);                                          \
        p_ += __shfl_xor(p_, 2);                                          \
        p_ += __shfl_xor(p_, 1);                                          \
        float nm_ = fmaxf(m##X, p_);                                      \
        float sc_ = __expf(m##X - nm_);                                   \
        float pe_ = __expf(p_ - nm_);                                     \
        d##X = d##X * sc_ + pe_;                                          \
        float hx0 = bflo(hu##X.x), hx1 = bfhi(hu##X.x);                   \
        float hx2 = bflo(hu##X.y), hx3 = bfhi(hu##X.y);                   \
        a##X.x = fmaf(a##X.x, sc_, pe_ * hx0);                            \
        a##X.y = fmaf(a##X.y, sc_, pe_ * hx1);                            \
        a##X.z = fmaf(a##X.z, sc_, pe_ * hx2);                            \
        a##X.w = fmaf(a##X.w, sc_, pe_ * hx3);                            \
        m##X = nm_; }

    #define ROT(X, Y) { e##X = e##Y; pu##X = pu##Y; hu##X = hu##Y;        \
        f##X##0 = f##Y##0; f##X##1 = f##Y##1; f##X##2 = f##Y##2;          \
        f##X##3 = f##Y##3; f##X##4 = f##Y##4; f##X##5 = f##Y##5;          \
        f##X##6 = f##Y##6; }

    DSTR(A) DSTR(B) DSTR(C) DSTR(D)

    LOADE(0, A);
    if (deg > 1) LOADE(1, B);
    if (deg > 2) LOADE(2, C);
    if (deg > 3) LOADE(3, D);

    for (int k = 0;; k++) {
        int base = 4 * k;
        DNXT(An) DNXT(Bn) DNXT(Cn) DNXT(Dn)
        if (base + 4 < deg) LOADE(base + 4, An);
        if (base + 5 < deg) LOADE(base + 5, Bn);
        if (base + 6 < deg) LOADE(base + 6, Cn);
        if (base + 7 < deg) LOADE(base + 7, Dn);

        PROC(A);
        if (base + 1 < deg) PROC(B);
        if (base + 2 < deg) PROC(C);
        if (base + 3 < deg) PROC(D);

        if (base + 4 >= deg) break;
        ROT(A, An); ROT(B, Bn); ROT(C, Cn); ROT(D, Dn);
    }

    float nm = fmaxf(fmaxf(mA, mB), fmaxf(mC, mD));
    float scA = __expf(mA - nm), scB = __expf(mB - nm);
    float scC = __expf(mC - nm), scD = __expf(mD - nm);
    float den = dA * scA + dB * scB + dC * scC + dD * scD;
    float r = 1.f / den;
    f32x4 acc;
    acc[0] = (aA.x * scA + aB.x * scB + aC.x * scC + aD.x * scD) * r;
    acc[1] = (aA.y * scA + aB.y * scB + aC.y * scC + aD.y * scD) * r;
    acc[2] = (aA.z * scA + aB.z * scB + aC.z * scC + aD.z * scD) * r;
    acc[3] = (aA.w * scA + aB.w * scB + aC.w * scC + aD.w * scD) * r;
    stream_store16(Obase, acc);

    #undef DSTR
    #undef DNXT
    #undef LOADE
    #undef PROC
    #undef ROT
}

// ---------------------------------------------------------------------------
extern "C" void kernel_launch(void* const* d_in, const int* in_sizes, int n_in,
                              void* d_out, int out_size, void* d_ws, size_t ws_size,
                              hipStream_t stream)
{
    const float* nfeats = (const float*)d_in[0];
    const float* efeats = (const float*)d_in[1];
    const int*   src    = (const int*)d_in[2];
    const int*   dst    = (const int*)d_in[3];
    const float* Wn     = (const float*)d_in[4];
    const float* bn     = (const float*)d_in[5];
    const float* We     = (const float*)d_in[6];
    const float* Wa     = (const float*)d_in[7];

    int N = in_sizes[0] / 128;
    int E = in_sizes[2];

    char* ws = (char*)d_ws;
    size_t off = 0;
    unsigned short* PH  = (unsigned short*)(ws + off); off += (size_t)N * 384 * 2;
    unsigned short* Qbf = (unsigned short*)(ws + off); off += (size_t)N * 128 * 2;
    short* Btg   = (short*)(ws + off); off += (size_t)512 * 128 * 2;
    int* REC       = (int*)(ws + off); off += (size_t)E * 48;
    unsigned short* tmp = (unsigned short*)(ws + off); off += (size_t)E * 2;
    int* deg       = (int*)(ws + off); off += (size_t)(N + 1) * 4;
    int* row_start = (int*)(ws + off); off += (size_t)(N + 1) * 4;
    int* bsum      = (int*)(ws + off); off += 1024;

    float* h_out = (float*)d_out;                       // [N, 4, 64]
    float* f_out = (float*)d_out + (size_t)N * 256;     // [E, 4, 32]

    zero_kernel<<<(N + 255) / 256, 256, 0, stream>>>(deg, N);

    bt_prep<<<256, 256, 0, stream>>>(Wn, We, Btg);

    dim3 g2((N + 63) / 64, 4);
    gemm_mfma<<<g2, 256, 0, stream>>>(nfeats, bn, Btg, PH, Qbf, N);

    scatter1_kernel<<<(E + 255) / 256, 256, 0, stream>>>(dst, deg, tmp, E);

    int nb = (N + 1023) / 1024;
    scan_sum<<<nb, 256, 0, stream>>>(deg, bsum, N);
    scan_write<<<nb, 256, 0, stream>>>(deg, bsum, row_start, N, nb);

    scatter2_kernel<<<(E + 255) / 256, 256, 0, stream>>>(dst, src, efeats,
                                                         row_start, tmp, REC, E);

    fused_kernel<<<N, 64, 0, stream>>>(row_start, REC,
                                       PH, Qbf, We, Wa,
                                       f_out, h_out, N);
}